// Round 2
// baseline (233.885 us; speedup 1.0000x reference)
//
#include <hip/hip_runtime.h>
#include <hip/hip_bf16.h>

// B=2, S=2048, D=1024, H=16, Hd=64
// cvt -> QKV GEMM (bf16 MFMA) -> per-head LN -> V transpose ->
// flash attention (swapped-QK, in-register softmax, 32x32x16 MFMA) -> proj GEMM

typedef __attribute__((ext_vector_type(8)))  short bf16x8;   // 8 bf16 (4 VGPRs)
typedef __attribute__((ext_vector_type(4)))  float f32x4;
typedef __attribute__((ext_vector_type(16))) float f32x16;

__device__ __forceinline__ unsigned short f2bf(float f) {
  union { float f; unsigned u; } v; v.f = f;
  unsigned r = v.u + 0x7FFFu + ((v.u >> 16) & 1u);
  return (unsigned short)(r >> 16);
}

// pack two f32 -> one dword of 2 bf16 (lo = a, hi = b)
__device__ __forceinline__ unsigned pkbf(float a, float b) {
  unsigned r;
  asm("v_cvt_pk_bf16_f32 %0, %1, %2" : "=v"(r) : "v"(a), "v"(b));
  return r;
}

// ---------------- fp32 -> bf16 convert ----------------
__global__ __launch_bounds__(256) void k_cvt(const float* __restrict__ s,
                                             unsigned short* __restrict__ d,
                                             int n4) {
  int i = blockIdx.x * 256 + threadIdx.x;
  if (i >= n4) return;
  float4 v = ((const float4*)s)[i];
  ushort4 o;
  o.x = f2bf(v.x); o.y = f2bf(v.y); o.z = f2bf(v.z); o.w = f2bf(v.w);
  ((ushort4*)d)[i] = o;
}

// ---------------- NT bf16 GEMM (unchanged from r1) ----------------
__global__ __launch_bounds__(256) void k_gemm_nt(
    const unsigned short* __restrict__ A, const unsigned short* __restrict__ B,
    const float* __restrict__ bias, float* __restrict__ C, int M, int N, int K)
{
  __shared__ unsigned short lA[128 * 72];
  __shared__ unsigned short lB[128 * 72];
  int tid = threadIdx.x;
  int lane = tid & 63, wid = tid >> 6;
  int lg = lane >> 4, lo = lane & 15;
  int wm = wid >> 1, wn = wid & 1;
  int m0 = blockIdx.y * 128, n0 = blockIdx.x * 128;
  f32x4 acc[4][4];
#pragma unroll
  for (int i = 0; i < 4; ++i)
#pragma unroll
    for (int j = 0; j < 4; ++j) acc[i][j] = (f32x4){0.f, 0.f, 0.f, 0.f};

  for (int kt = 0; kt < K; kt += 64) {
    __syncthreads();
#pragma unroll
    for (int mth = 0; mth < 4; ++mth) {
      int cid = tid + 256 * mth;
      int row = cid >> 3, c = cid & 7;
      bf16x8 av = *(const bf16x8*)(A + (size_t)(m0 + row) * K + kt + c * 8);
      *(bf16x8*)&lA[row * 72 + c * 8] = av;
      bf16x8 bv = *(const bf16x8*)(B + (size_t)(n0 + row) * K + kt + c * 8);
      *(bf16x8*)&lB[row * 72 + c * 8] = bv;
    }
    __syncthreads();
#pragma unroll
    for (int ks = 0; ks < 2; ++ks) {
      bf16x8 af[4], bfr[4];
#pragma unroll
      for (int i = 0; i < 4; ++i)
        af[i] = *(const bf16x8*)&lA[(wm * 64 + i * 16 + lo) * 72 + ks * 32 + lg * 8];
#pragma unroll
      for (int j = 0; j < 4; ++j)
        bfr[j] = *(const bf16x8*)&lB[(wn * 64 + j * 16 + lo) * 72 + ks * 32 + lg * 8];
#pragma unroll
      for (int i = 0; i < 4; ++i)
#pragma unroll
        for (int j = 0; j < 4; ++j)
          acc[i][j] = __builtin_amdgcn_mfma_f32_16x16x32_bf16(af[i], bfr[j], acc[i][j], 0, 0, 0);
    }
  }
#pragma unroll
  for (int j = 0; j < 4; ++j) {
    int col = n0 + wn * 64 + j * 16 + lo;
    float bb = bias[col];
#pragma unroll
    for (int i = 0; i < 4; ++i)
#pragma unroll
      for (int r = 0; r < 4; ++r) {
        int row = m0 + wm * 64 + i * 16 + lg * 4 + r;
        C[(size_t)row * N + col] = acc[i][j][r] + bb;
      }
  }
}

// ---------------- per-head LN + split (unchanged from r1) ----------------
__global__ __launch_bounds__(256) void k_ln(
    const float* __restrict__ qkv,
    const float* __restrict__ qg, const float* __restrict__ qb,
    const float* __restrict__ kg, const float* __restrict__ kb,
    unsigned short* __restrict__ q, unsigned short* __restrict__ k,
    unsigned short* __restrict__ v)
{
  int wg = blockIdx.x * 4 + (threadIdx.x >> 6);
  int lane = threadIdx.x & 63;
  int h = wg & 15;
  int m = wg >> 4;
  const float* base = qkv + (size_t)m * 3072 + h * 64 + lane;
  float xq = base[0];
  float xk = base[1024];
  float xv = base[2048];
  float muq = xq, muk = xk;
#pragma unroll
  for (int t = 32; t; t >>= 1) { muq += __shfl_xor(muq, t, 64); muk += __shfl_xor(muk, t, 64); }
  muq *= (1.0f / 64.0f); muk *= (1.0f / 64.0f);
  float dq = xq - muq, dk = xk - muk;
  float vq = dq * dq, vk = dk * dk;
#pragma unroll
  for (int t = 32; t; t >>= 1) { vq += __shfl_xor(vq, t, 64); vk += __shfl_xor(vk, t, 64); }
  vq *= (1.0f / 64.0f); vk *= (1.0f / 64.0f);
  float yq = dq * rsqrtf(vq + 1e-5f) * qg[lane] + qb[lane];
  float yk = dk * rsqrtf(vk + 1e-5f) * kg[lane] + kb[lane];
  int b = m >> 11, s = m & 2047;
  size_t o = (((size_t)(b * 16 + h)) * 2048 + s) * 64 + lane;
  q[o] = f2bf(yq * 0.125f);
  k[o] = f2bf(yk);
  v[o] = f2bf(xv);
}

// ---------------- V transpose: [bh][s][64] -> [bh][64][s] ----------------
__global__ __launch_bounds__(256) void k_tr(const unsigned short* __restrict__ V,
                                            unsigned short* __restrict__ VT)
{
  __shared__ unsigned short t[64 * 72];
  int bh = blockIdx.y;
  int s0 = blockIdx.x * 64;
  int tid = threadIdx.x;
  // load 64x64 tile, b128 coalesced
#pragma unroll
  for (int it = 0; it < 2; ++it) {
    int idx = tid + 256 * it;
    int r = idx >> 3, cc = idx & 7;
    *(bf16x8*)&t[r * 72 + cc * 8] = *(const bf16x8*)(V + ((size_t)bh * 2048 + s0 + r) * 64 + cc * 8);
  }
  __syncthreads();
  // write transposed: thread owns column d = tid&63 (2-way LDS banks = free)
  int d = tid & 63;
#pragma unroll
  for (int it = 0; it < 2; ++it) {
    int cc = (tid >> 6) + 4 * it;
    bf16x8 o;
#pragma unroll
    for (int j = 0; j < 8; ++j) o[j] = (short)t[(cc * 8 + j) * 72 + d];
    *(bf16x8*)(VT + ((size_t)bh * 64 + d) * 2048 + s0 + cc * 8) = o;
  }
}

// ---------------- flash attention: swapped-QK, in-register softmax ----------------
// grid (S/128, BH), 256 thr = 4 waves x 32 q-rows. No LDS, no barriers.
// QK^T: mfma(K,Q) -> S^T[kv][q], col=lane&31=q (lane-local row stats).
// PV:   mfma(V^T, P) -> O^T[d][q]; P B-frag built by cvt_pk + shfl_xor(32).
__global__ __launch_bounds__(256) void k_attn(
    const unsigned short* __restrict__ Q,   // [BH][S][64] (pre-scaled by 0.125)
    const unsigned short* __restrict__ K,   // [BH][S][64]
    const unsigned short* __restrict__ VT,  // [BH][64][S]
    unsigned short* __restrict__ O)         // [B*S][1024] bf16
{
  int tid = threadIdx.x;
  int wid = tid >> 6, lane = tid & 63;
  int l31 = lane & 31, hi = lane >> 5;
  int bh = blockIdx.y;
  int q = blockIdx.x * 128 + wid * 32 + l31;

  // hoist Q B-frags: B[col=q][k=16s+8hi+j]
  const unsigned short* qp = Q + ((size_t)bh * 2048 + q) * 64 + hi * 8;
  bf16x8 qf[4];
#pragma unroll
  for (int s = 0; s < 4; ++s) qf[s] = *(const bf16x8*)(qp + 16 * s);

  const unsigned short* kp = K + (size_t)bh * 2048 * 64 + (size_t)l31 * 64 + hi * 8;
  const unsigned short* vp = VT + (size_t)bh * 64 * 2048 + (size_t)l31 * 2048 + hi * 8;

  float m = -1e30f, lsum = 0.0f;
  f32x16 o0, o1;
#pragma unroll
  for (int i = 0; i < 16; ++i) { o0[i] = 0.f; o1[i] = 0.f; }

  for (int kv0 = 0; kv0 < 2048; kv0 += 64) {
    // ---- QK^T: two 32-kv fragments ----
    f32x16 s0, s1;
#pragma unroll
    for (int i = 0; i < 16; ++i) { s0[i] = 0.f; s1[i] = 0.f; }
#pragma unroll
    for (int s = 0; s < 4; ++s) {
      bf16x8 k0 = *(const bf16x8*)(kp + (size_t)kv0 * 64 + 16 * s);
      bf16x8 k1 = *(const bf16x8*)(kp + (size_t)(kv0 + 32) * 64 + 16 * s);
      s0 = __builtin_amdgcn_mfma_f32_32x32x16_bf16(k0, qf[s], s0, 0, 0, 0);
      s1 = __builtin_amdgcn_mfma_f32_32x32x16_bf16(k1, qf[s], s1, 0, 0, 0);
    }

    // ---- online softmax (lane-local; q = l31, halves split kv) ----
    float pm = s0[0];
#pragma unroll
    for (int i = 1; i < 16; ++i) pm = fmaxf(pm, s0[i]);
#pragma unroll
    for (int i = 0; i < 16; ++i) pm = fmaxf(pm, s1[i]);
    pm = fmaxf(pm, __shfl_xor(pm, 32, 64));

    if (!__all(pm - m <= 8.0f)) {           // defer-max (T13)
      float mn = fmaxf(m, pm);
      float fac = __expf(m - mn);
      m = mn;
      lsum *= fac;
#pragma unroll
      for (int i = 0; i < 16; ++i) { o0[i] *= fac; o1[i] *= fac; }
    }

    float ps = 0.f;
#pragma unroll
    for (int i = 0; i < 16; ++i) { s0[i] = __expf(s0[i] - m); ps += s0[i]; }
#pragma unroll
    for (int i = 0; i < 16; ++i) { s1[i] = __expf(s1[i] - m); ps += s1[i]; }
    ps += __shfl_xor(ps, 32, 64);
    lsum += ps;

    // ---- PV: O^T[d][q] += V^T-frag x P-frag, 4 K-steps of 16 kv ----
#pragma unroll
    for (int s = 0; s < 4; ++s) {
      const f32x16& sf = (s < 2) ? s0 : s1;
      const int rb = (s & 1) * 8;
      // own kv' = {rb-group}: a = kv' 16(s&1)+4hi+{0..3}, b = +8
      unsigned a0 = pkbf(sf[rb + 0], sf[rb + 1]);
      unsigned a1 = pkbf(sf[rb + 2], sf[rb + 3]);
      unsigned b0 = pkbf(sf[rb + 4], sf[rb + 5]);
      unsigned b1 = pkbf(sf[rb + 6], sf[rb + 7]);
      // partner needs: hi=0's wB (for hi=1) / hi=1's wA (for hi=0)
      unsigned t0 = hi ? a0 : b0, t1 = hi ? a1 : b1;
      unsigned r0 = __shfl_xor(t0, 32, 64);
      unsigned r1 = __shfl_xor(t1, 32, 64);
      unsigned w0 = hi ? r0 : a0, w1 = hi ? r1 : a1;
      unsigned w2 = hi ? b0 : r0, w3 = hi ? b1 : r1;
      union { unsigned u[4]; bf16x8 v; } pu;
      pu.u[0] = w0; pu.u[1] = w1; pu.u[2] = w2; pu.u[3] = w3;
      bf16x8 vt0 = *(const bf16x8*)(vp + kv0 + 16 * s);
      bf16x8 vt1 = *(const bf16x8*)(vp + 32 * 2048 + kv0 + 16 * s);
      o0 = __builtin_amdgcn_mfma_f32_32x32x16_bf16(vt0, pu.v, o0, 0, 0, 0);
      o1 = __builtin_amdgcn_mfma_f32_32x32x16_bf16(vt1, pu.v, o1, 0, 0, 0);
    }
  }

  // ---- epilogue: O[q][h*64+d] = O^T/lsum; d = (r&3)+8(r>>2)+4hi+32t ----
  float inv = 1.0f / lsum;
  int b = bh >> 4, h = bh & 15;
  unsigned short* ob = O + ((size_t)(b * 2048 + q)) * 1024 + h * 64;
#pragma unroll
  for (int g = 0; g < 4; ++g) {
    uint2 w;
    w.x = pkbf(o0[4 * g + 0] * inv, o0[4 * g + 1] * inv);
    w.y = pkbf(o0[4 * g + 2] * inv, o0[4 * g + 3] * inv);
    *(uint2*)(ob + 8 * g + 4 * hi) = w;
    w.x = pkbf(o1[4 * g + 0] * inv, o1[4 * g + 1] * inv);
    w.y = pkbf(o1[4 * g + 2] * inv, o1[4 * g + 3] * inv);
    *(uint2*)(ob + 32 + 8 * g + 4 * hi) = w;
  }
}

extern "C" void kernel_launch(void* const* d_in, const int* in_sizes, int n_in,
                              void* d_out, int out_size, void* d_ws, size_t ws_size,
                              hipStream_t stream)
{
  (void)in_sizes; (void)n_in; (void)out_size; (void)ws_size;
  const float* x      = (const float*)d_in[0];
  const float* w_qkv  = (const float*)d_in[1];
  const float* b_qkv  = (const float*)d_in[2];
  const float* w_proj = (const float*)d_in[3];
  const float* b_proj = (const float*)d_in[4];
  const float* q_g    = (const float*)d_in[5];
  const float* q_b    = (const float*)d_in[6];
  const float* k_g    = (const float*)d_in[7];
  const float* k_b    = (const float*)d_in[8];
  float* out = (float*)d_out;

  // workspace layout (96 MB); vt aliases dead qkv region
  char* p = (char*)d_ws;
  unsigned short* x_bf  = (unsigned short*)p;  p += (size_t)4096 * 1024 * 2;   // 8MB
  unsigned short* wq_bf = (unsigned short*)p;  p += (size_t)3072 * 1024 * 2;   // 6MB
  unsigned short* wp_bf = (unsigned short*)p;  p += (size_t)1024 * 1024 * 2;   // 2MB
  float*          qkv   = (float*)p;           p += (size_t)4096 * 3072 * 4;   // 48MB
  unsigned short* qh    = (unsigned short*)p;  p += (size_t)32 * 2048 * 64 * 2;
  unsigned short* kh    = (unsigned short*)p;  p += (size_t)32 * 2048 * 64 * 2;
  unsigned short* vh    = (unsigned short*)p;  p += (size_t)32 * 2048 * 64 * 2;
  unsigned short* ao    = (unsigned short*)p;  p += (size_t)4096 * 1024 * 2;
  unsigned short* vt    = (unsigned short*)qkv;   // reuse: qkv dead after k_ln

  k_cvt<<<4096, 256, 0, stream>>>(x,      x_bf,  1048576);
  k_cvt<<<3072, 256, 0, stream>>>(w_qkv,  wq_bf,  786432);
  k_cvt<<<1024, 256, 0, stream>>>(w_proj, wp_bf,  262144);

  k_gemm_nt<<<dim3(24, 32), 256, 0, stream>>>(x_bf, wq_bf, b_qkv, qkv, 4096, 3072, 1024);
  k_ln<<<16384, 256, 0, stream>>>(qkv, q_g, q_b, k_g, k_b, qh, kh, vh);
  k_tr<<<dim3(32, 32), 256, 0, stream>>>(vh, vt);
  k_attn<<<dim3(16, 32), 256, 0, stream>>>(qh, kh, vt, ao);
  k_gemm_nt<<<dim3(8, 32), 256, 0, stream>>>(ao, wp_bf, b_proj, out, 4096, 1024, 1024);
}

// Round 3
// 170.015 us; speedup vs baseline: 1.3757x; 1.3757x over previous
//
#include <hip/hip_runtime.h>
#include <hip/hip_bf16.h>

// B=2, S=2048, D=1024, H=16, Hd=64
// cvt -> QKV GEMM (bf16 MFMA) -> per-head LN (q pre-scaled by 0.125*log2e) ->
// V transpose -> flash attention (swapped-QK, LDS double-buffered K/VT,
// KVBLK=128, XCD-swizzled blocks) -> proj GEMM

typedef __attribute__((ext_vector_type(8)))  short bf16x8;   // 8 bf16 (4 VGPRs)
typedef __attribute__((ext_vector_type(4)))  float f32x4;
typedef __attribute__((ext_vector_type(16))) float f32x16;

__device__ __forceinline__ unsigned short f2bf(float f) {
  union { float f; unsigned u; } v; v.f = f;
  unsigned r = v.u + 0x7FFFu + ((v.u >> 16) & 1u);
  return (unsigned short)(r >> 16);
}

__device__ __forceinline__ unsigned pkbf(float a, float b) {
  unsigned r;
  asm("v_cvt_pk_bf16_f32 %0, %1, %2" : "=v"(r) : "v"(a), "v"(b));
  return r;
}

// ---------------- fp32 -> bf16 convert ----------------
__global__ __launch_bounds__(256) void k_cvt(const float* __restrict__ s,
                                             unsigned short* __restrict__ d,
                                             int n4) {
  int i = blockIdx.x * 256 + threadIdx.x;
  if (i >= n4) return;
  float4 v = ((const float4*)s)[i];
  ushort4 o;
  o.x = f2bf(v.x); o.y = f2bf(v.y); o.z = f2bf(v.z); o.w = f2bf(v.w);
  ((ushort4*)d)[i] = o;
}

// ---------------- NT bf16 GEMM (unchanged) ----------------
__global__ __launch_bounds__(256) void k_gemm_nt(
    const unsigned short* __restrict__ A, const unsigned short* __restrict__ B,
    const float* __restrict__ bias, float* __restrict__ C, int M, int N, int K)
{
  __shared__ unsigned short lA[128 * 72];
  __shared__ unsigned short lB[128 * 72];
  int tid = threadIdx.x;
  int lane = tid & 63, wid = tid >> 6;
  int lg = lane >> 4, lo = lane & 15;
  int wm = wid >> 1, wn = wid & 1;
  int m0 = blockIdx.y * 128, n0 = blockIdx.x * 128;
  f32x4 acc[4][4];
#pragma unroll
  for (int i = 0; i < 4; ++i)
#pragma unroll
    for (int j = 0; j < 4; ++j) acc[i][j] = (f32x4){0.f, 0.f, 0.f, 0.f};

  for (int kt = 0; kt < K; kt += 64) {
    __syncthreads();
#pragma unroll
    for (int mth = 0; mth < 4; ++mth) {
      int cid = tid + 256 * mth;
      int row = cid >> 3, c = cid & 7;
      bf16x8 av = *(const bf16x8*)(A + (size_t)(m0 + row) * K + kt + c * 8);
      *(bf16x8*)&lA[row * 72 + c * 8] = av;
      bf16x8 bv = *(const bf16x8*)(B + (size_t)(n0 + row) * K + kt + c * 8);
      *(bf16x8*)&lB[row * 72 + c * 8] = bv;
    }
    __syncthreads();
#pragma unroll
    for (int ks = 0; ks < 2; ++ks) {
      bf16x8 af[4], bfr[4];
#pragma unroll
      for (int i = 0; i < 4; ++i)
        af[i] = *(const bf16x8*)&lA[(wm * 64 + i * 16 + lo) * 72 + ks * 32 + lg * 8];
#pragma unroll
      for (int j = 0; j < 4; ++j)
        bfr[j] = *(const bf16x8*)&lB[(wn * 64 + j * 16 + lo) * 72 + ks * 32 + lg * 8];
#pragma unroll
      for (int i = 0; i < 4; ++i)
#pragma unroll
        for (int j = 0; j < 4; ++j)
          acc[i][j] = __builtin_amdgcn_mfma_f32_16x16x32_bf16(af[i], bfr[j], acc[i][j], 0, 0, 0);
    }
  }
#pragma unroll
  for (int j = 0; j < 4; ++j) {
    int col = n0 + wn * 64 + j * 16 + lo;
    float bb = bias[col];
#pragma unroll
    for (int i = 0; i < 4; ++i)
#pragma unroll
      for (int r = 0; r < 4; ++r) {
        int row = m0 + wm * 64 + i * 16 + lg * 4 + r;
        C[(size_t)row * N + col] = acc[i][j][r] + bb;
      }
  }
}

// ---------------- per-head LN + split ----------------
// q pre-scaled by 0.125 * log2(e) so attention softmax can use exp2
__global__ __launch_bounds__(256) void k_ln(
    const float* __restrict__ qkv,
    const float* __restrict__ qg, const float* __restrict__ qb,
    const float* __restrict__ kg, const float* __restrict__ kb,
    unsigned short* __restrict__ q, unsigned short* __restrict__ k,
    unsigned short* __restrict__ v)
{
  int wg = blockIdx.x * 4 + (threadIdx.x >> 6);
  int lane = threadIdx.x & 63;
  int h = wg & 15;
  int m = wg >> 4;
  const float* base = qkv + (size_t)m * 3072 + h * 64 + lane;
  float xq = base[0];
  float xk = base[1024];
  float xv = base[2048];
  float muq = xq, muk = xk;
#pragma unroll
  for (int t = 32; t; t >>= 1) { muq += __shfl_xor(muq, t, 64); muk += __shfl_xor(muk, t, 64); }
  muq *= (1.0f / 64.0f); muk *= (1.0f / 64.0f);
  float dq = xq - muq, dk = xk - muk;
  float vq = dq * dq, vk = dk * dk;
#pragma unroll
  for (int t = 32; t; t >>= 1) { vq += __shfl_xor(vq, t, 64); vk += __shfl_xor(vk, t, 64); }
  vq *= (1.0f / 64.0f); vk *= (1.0f / 64.0f);
  float yq = dq * rsqrtf(vq + 1e-5f) * qg[lane] + qb[lane];
  float yk = dk * rsqrtf(vk + 1e-5f) * kg[lane] + kb[lane];
  int b = m >> 11, s = m & 2047;
  size_t o = (((size_t)(b * 16 + h)) * 2048 + s) * 64 + lane;
  q[o] = f2bf(yq * 0.18033688f);   // 0.125 * log2(e)
  k[o] = f2bf(yk);
  v[o] = f2bf(xv);
}

// ---------------- V transpose: [bh][s][64] -> [bh][64][s] ----------------
__global__ __launch_bounds__(256) void k_tr(const unsigned short* __restrict__ V,
                                            unsigned short* __restrict__ VT)
{
  __shared__ unsigned short t[64 * 72];
  int bh = blockIdx.y;
  int s0 = blockIdx.x * 64;
  int tid = threadIdx.x;
#pragma unroll
  for (int it = 0; it < 2; ++it) {
    int idx = tid + 256 * it;
    int r = idx >> 3, cc = idx & 7;
    *(bf16x8*)&t[r * 72 + cc * 8] = *(const bf16x8*)(V + ((size_t)bh * 2048 + s0 + r) * 64 + cc * 8);
  }
  __syncthreads();
  int d = tid & 63;
#pragma unroll
  for (int it = 0; it < 2; ++it) {
    int cc = (tid >> 6) + 4 * it;
    bf16x8 o;
#pragma unroll
    for (int j = 0; j < 8; ++j) o[j] = (short)t[(cc * 8 + j) * 72 + d];
    *(bf16x8*)(VT + ((size_t)bh * 64 + d) * 2048 + s0 + cc * 8) = o;
  }
}

// ---------------- flash attention v3 ----------------
// 1D grid 512 blocks (XCD-swizzled), 256 thr = 4 waves x 32 q.
// KVBLK=128; K [128][72] and VT [64][136] double-buffered in LDS,
// staged global->reg one tile ahead, reg->LDS after the single barrier.
__global__ __launch_bounds__(256, 2) void k_attn(
    const unsigned short* __restrict__ Q,   // [BH][S][64] (pre-scaled)
    const unsigned short* __restrict__ K,   // [BH][S][64]
    const unsigned short* __restrict__ VT,  // [BH][64][S]
    unsigned short* __restrict__ O)         // [B*S][1024] bf16
{
  __shared__ unsigned short lK[2][128 * 72];
  __shared__ unsigned short lV[2][64 * 136];

  int tid = threadIdx.x;
  int wid = tid >> 6, lane = tid & 63;
  int l31 = lane & 31, hi = lane >> 5;

  // XCD-aware bijective swizzle: co-locate each head's 16 blocks on one XCD
  int id = blockIdx.x;                       // 0..511
  int nid = (id & 7) * 64 + (id >> 3);
  int bh = nid >> 4;
  int q0 = (nid & 15) << 7;                  // 128 q-rows per block
  int q = q0 + wid * 32 + l31;

  // hoist Q B-frags: B[col=q][k=16s+8hi+j]
  const unsigned short* qp = Q + ((size_t)bh * 2048 + q) * 64 + hi * 8;
  bf16x8 qf[4];
#pragma unroll
  for (int s = 0; s < 4; ++s) qf[s] = *(const bf16x8*)(qp + 16 * s);

  const unsigned short* kb = K + (size_t)bh * 2048 * 64;
  const unsigned short* vb = VT + (size_t)bh * 64 * 2048;

  // per-thread staging coords
  int krow[4], kc[4], vrow[4], vc[4];
#pragma unroll
  for (int i = 0; i < 4; ++i) {
    int cid = tid + 256 * i;
    krow[i] = cid >> 3; kc[i] = cid & 7;     // K: 128 rows x 8 chunks
    vrow[i] = cid >> 4; vc[i] = cid & 15;    // VT: 64 rows x 16 chunks
  }

  float m = -1e30f, lsum = 0.0f;
  f32x16 o0, o1;
#pragma unroll
  for (int i = 0; i < 16; ++i) { o0[i] = 0.f; o1[i] = 0.f; }

  // prologue: stage tile 0 into buf 0
  bf16x8 kr[4], vr[4];
#pragma unroll
  for (int i = 0; i < 4; ++i) {
    kr[i] = *(const bf16x8*)(kb + (size_t)krow[i] * 64 + kc[i] * 8);
    vr[i] = *(const bf16x8*)(vb + (size_t)vrow[i] * 2048 + vc[i] * 8);
  }
#pragma unroll
  for (int i = 0; i < 4; ++i) {
    *(bf16x8*)&lK[0][krow[i] * 72 + kc[i] * 8] = kr[i];
    *(bf16x8*)&lV[0][vrow[i] * 136 + vc[i] * 8] = vr[i];
  }

  int p = 0;
  for (int t = 0; t < 16; ++t) {
    // issue next tile's global loads (consumed after this tile's compute)
    if (t < 15) {
      int kvn = (t + 1) << 7;
#pragma unroll
      for (int i = 0; i < 4; ++i) {
        kr[i] = *(const bf16x8*)(kb + (size_t)(kvn + krow[i]) * 64 + kc[i] * 8);
        vr[i] = *(const bf16x8*)(vb + (size_t)vrow[i] * 2048 + kvn + vc[i] * 8);
      }
    }
    __syncthreads();   // buf[p] writes visible; prior reads of buf[p^1] done

    const unsigned short* bK = lK[p];
    const unsigned short* bV = lV[p];

    // ---- QK^T: 4 fragments of 32 kv, K-dim = 64 (4 MFMA steps each) ----
    f32x16 sc[4];
#pragma unroll
    for (int c = 0; c < 4; ++c)
#pragma unroll
      for (int i = 0; i < 16; ++i) sc[c][i] = 0.f;
#pragma unroll
    for (int c = 0; c < 4; ++c)
#pragma unroll
      for (int s = 0; s < 4; ++s) {
        bf16x8 kf = *(const bf16x8*)&bK[(c * 32 + l31) * 72 + (2 * s + hi) * 8];
        sc[c] = __builtin_amdgcn_mfma_f32_32x32x16_bf16(kf, qf[s], sc[c], 0, 0, 0);
      }

    // ---- online softmax (log2 domain; lane owns q-row l31, halves split kv) ----
    float pm = sc[0][0];
#pragma unroll
    for (int c = 0; c < 4; ++c)
#pragma unroll
      for (int i = 0; i < 16; ++i) pm = fmaxf(pm, sc[c][i]);
    pm = fmaxf(pm, __shfl_xor(pm, 32, 64));

    if (!__all(pm - m <= 8.0f)) {            // defer-max (T13)
      float mn = fmaxf(m, pm);
      float fac = exp2f(m - mn);
      m = mn;
      lsum *= fac;
#pragma unroll
      for (int i = 0; i < 16; ++i) { o0[i] *= fac; o1[i] *= fac; }
    }

    float ps = 0.f;
#pragma unroll
    for (int c = 0; c < 4; ++c)
#pragma unroll
      for (int i = 0; i < 16; ++i) {
        float pe = exp2f(sc[c][i] - m);
        sc[c][i] = pe;
        ps += pe;
      }
    ps += __shfl_xor(ps, 32, 64);
    lsum += ps;

    // ---- PV: 8 K-steps of 16 kv; P B-frag via cvt_pk + shfl_xor(32) ----
#pragma unroll
    for (int s = 0; s < 8; ++s) {
      const f32x16& sf = sc[s >> 1];
      const int rb = (s & 1) * 8;
      unsigned a0 = pkbf(sf[rb + 0], sf[rb + 1]);
      unsigned a1 = pkbf(sf[rb + 2], sf[rb + 3]);
      unsigned b0 = pkbf(sf[rb + 4], sf[rb + 5]);
      unsigned b1 = pkbf(sf[rb + 6], sf[rb + 7]);
      unsigned t0 = hi ? a0 : b0, t1 = hi ? a1 : b1;
      unsigned r0 = __shfl_xor(t0, 32, 64);
      unsigned r1 = __shfl_xor(t1, 32, 64);
      unsigned w0 = hi ? r0 : a0, w1 = hi ? r1 : a1;
      unsigned w2 = hi ? b0 : r0, w3 = hi ? b1 : r1;
      union { unsigned u[4]; bf16x8 v; } pu;
      pu.u[0] = w0; pu.u[1] = w1; pu.u[2] = w2; pu.u[3] = w3;
      bf16x8 v0 = *(const bf16x8*)&bV[l31 * 136 + (2 * s + hi) * 8];
      bf16x8 v1 = *(const bf16x8*)&bV[(l31 + 32) * 136 + (2 * s + hi) * 8];
      o0 = __builtin_amdgcn_mfma_f32_32x32x16_bf16(v0, pu.v, o0, 0, 0, 0);
      o1 = __builtin_amdgcn_mfma_f32_32x32x16_bf16(v1, pu.v, o1, 0, 0, 0);
    }

    // write next tile into the other buffer (its readers finished pre-barrier)
    if (t < 15) {
#pragma unroll
      for (int i = 0; i < 4; ++i) {
        *(bf16x8*)&lK[p ^ 1][krow[i] * 72 + kc[i] * 8] = kr[i];
        *(bf16x8*)&lV[p ^ 1][vrow[i] * 136 + vc[i] * 8] = vr[i];
      }
    }
    p ^= 1;
  }

  // ---- epilogue: O[q][h*64+d], d = (r&3)+8(r>>2)+4hi (+32 for o1) ----
  float inv = 1.0f / lsum;
  int b = bh >> 4, h = bh & 15;
  unsigned short* ob = O + ((size_t)(b * 2048 + q)) * 1024 + h * 64;
#pragma unroll
  for (int g = 0; g < 4; ++g) {
    uint2 w;
    w.x = pkbf(o0[4 * g + 0] * inv, o0[4 * g + 1] * inv);
    w.y = pkbf(o0[4 * g + 2] * inv, o0[4 * g + 3] * inv);
    *(uint2*)(ob + 8 * g + 4 * hi) = w;
    w.x = pkbf(o1[4 * g + 0] * inv, o1[4 * g + 1] * inv);
    w.y = pkbf(o1[4 * g + 2] * inv, o1[4 * g + 3] * inv);
    *(uint2*)(ob + 32 + 8 * g + 4 * hi) = w;
  }
}

extern "C" void kernel_launch(void* const* d_in, const int* in_sizes, int n_in,
                              void* d_out, int out_size, void* d_ws, size_t ws_size,
                              hipStream_t stream)
{
  (void)in_sizes; (void)n_in; (void)out_size; (void)ws_size;
  const float* x      = (const float*)d_in[0];
  const float* w_qkv  = (const float*)d_in[1];
  const float* b_qkv  = (const float*)d_in[2];
  const float* w_proj = (const float*)d_in[3];
  const float* b_proj = (const float*)d_in[4];
  const float* q_g    = (const float*)d_in[5];
  const float* q_b    = (const float*)d_in[6];
  const float* k_g    = (const float*)d_in[7];
  const float* k_b    = (const float*)d_in[8];
  float* out = (float*)d_out;

  char* p = (char*)d_ws;
  unsigned short* x_bf  = (unsigned short*)p;  p += (size_t)4096 * 1024 * 2;
  unsigned short* wq_bf = (unsigned short*)p;  p += (size_t)3072 * 1024 * 2;
  unsigned short* wp_bf = (unsigned short*)p;  p += (size_t)1024 * 1024 * 2;
  float*          qkv   = (float*)p;           p += (size_t)4096 * 3072 * 4;
  unsigned short* qh    = (unsigned short*)p;  p += (size_t)32 * 2048 * 64 * 2;
  unsigned short* kh    = (unsigned short*)p;  p += (size_t)32 * 2048 * 64 * 2;
  unsigned short* vh    = (unsigned short*)p;  p += (size_t)32 * 2048 * 64 * 2;
  unsigned short* ao    = (unsigned short*)p;  p += (size_t)4096 * 1024 * 2;
  unsigned short* vt    = (unsigned short*)qkv;   // qkv dead after k_ln

  k_cvt<<<4096, 256, 0, stream>>>(x,      x_bf,  1048576);
  k_cvt<<<3072, 256, 0, stream>>>(w_qkv,  wq_bf,  786432);
  k_cvt<<<1024, 256, 0, stream>>>(w_proj, wp_bf,  262144);

  k_gemm_nt<<<dim3(24, 32), 256, 0, stream>>>(x_bf, wq_bf, b_qkv, qkv, 4096, 3072, 1024);
  k_ln<<<16384, 256, 0, stream>>>(qkv, q_g, q_b, k_g, k_b, qh, kh, vh);
  k_tr<<<dim3(32, 32), 256, 0, stream>>>(vh, vt);
  k_attn<<<512, 256, 0, stream>>>(qh, kh, vt, ao);
  k_gemm_nt<<<dim3(8, 32), 256, 0, stream>>>(ao, wp_bf, b_proj, out, 4096, 1024, 1024);
}

// Round 4
// 160.781 us; speedup vs baseline: 1.4547x; 1.0574x over previous
//
#include <hip/hip_runtime.h>
#include <hip/hip_bf16.h>

// B=2, S=2048, D=1024, H=16, Hd=64
// cvt -> QKV GEMM (bf16 MFMA, global_load_lds staging) -> fused per-head LN +
// V-transpose -> flash attention (swapped-QK, tree softmax, permlane32_swap
// P-assembly, LDS dbuf K/VT) -> proj GEMM

typedef __attribute__((ext_vector_type(8)))  short bf16x8;   // 8 bf16 (4 VGPRs)
typedef __attribute__((ext_vector_type(4)))  float f32x4;
typedef __attribute__((ext_vector_type(16))) float f32x16;

__device__ __forceinline__ unsigned short f2bf(float f) {
  union { float f; unsigned u; } v; v.f = f;
  unsigned r = v.u + 0x7FFFu + ((v.u >> 16) & 1u);
  return (unsigned short)(r >> 16);
}

__device__ __forceinline__ unsigned pkbf(float a, float b) {
  unsigned r;
  asm("v_cvt_pk_bf16_f32 %0, %1, %2" : "=v"(r) : "v"(a), "v"(b));
  return r;
}

// swap upper half of x with lower half of y: x'=(x.lo,y.lo), y'=(x.hi,y.hi)
__device__ __forceinline__ void pl32swap(unsigned& x, unsigned& y) {
  asm("v_permlane32_swap_b32 %0, %1" : "+v"(x), "+v"(y));
}

// async global->LDS DMA, 16B per lane (dest must be wave-uniform base + lane*16)
__device__ __forceinline__ void gld_lds16(const void* g, void* l) {
  __builtin_amdgcn_global_load_lds(
      (const __attribute__((address_space(1))) void*)g,
      (__attribute__((address_space(3))) void*)l, 16, 0, 0);
}

// ---------------- fp32 -> bf16 convert ----------------
__global__ __launch_bounds__(256) void k_cvt(const float* __restrict__ s,
                                             unsigned short* __restrict__ d,
                                             int n4) {
  int i = blockIdx.x * 256 + threadIdx.x;
  if (i >= n4) return;
  float4 v = ((const float4*)s)[i];
  ushort4 o;
  o.x = f2bf(v.x); o.y = f2bf(v.y); o.z = f2bf(v.z); o.w = f2bf(v.w);
  ((ushort4*)d)[i] = o;
}

// ---------------- NT bf16 GEMM with global_load_lds staging ----------------
// C[M][N] = A[M][K]*B[N][K]^T + bias. 256 thr, WM x WN waves, linear LDS (m97).
template<int BM, int BN, int WM, int WN>
__global__ __launch_bounds__(256) void k_gemm(
    const unsigned short* __restrict__ A, const unsigned short* __restrict__ B,
    const float* __restrict__ bias, float* __restrict__ C, int M, int N, int K)
{
  constexpr int FM = BM / WM / 16;
  constexpr int FN = BN / WN / 16;
  __shared__ unsigned short lA[BM * 64];
  __shared__ unsigned short lB[BN * 64];
  int tid = threadIdx.x;
  int lane = tid & 63, wid = tid >> 6;
  int lg = lane >> 4, lo = lane & 15;
  int wm = wid / WN, wn = wid % WN;
  int m0 = blockIdx.y * BM, n0 = blockIdx.x * BN;

  f32x4 acc[FM][FN];
#pragma unroll
  for (int i = 0; i < FM; ++i)
#pragma unroll
    for (int j = 0; j < FN; ++j) acc[i][j] = (f32x4){0.f, 0.f, 0.f, 0.f};

  const int srow = tid >> 3, scol = (tid & 7) * 8;   // 16B chunk coords

  for (int kt = 0; kt < K; kt += 64) {
    __syncthreads();                       // prior reads done before overwrite
#pragma unroll
    for (int i = 0; i < BM / 32; ++i)
      gld_lds16(A + (size_t)(m0 + srow + 32 * i) * K + kt + scol,
                &lA[(srow + 32 * i) * 64 + scol]);
#pragma unroll
    for (int i = 0; i < BN / 32; ++i)
      gld_lds16(B + (size_t)(n0 + srow + 32 * i) * K + kt + scol,
                &lB[(srow + 32 * i) * 64 + scol]);
    __syncthreads();                       // vmcnt(0) drained before barrier

#pragma unroll
    for (int ks = 0; ks < 2; ++ks) {
      bf16x8 af[FM], bfr[FN];
#pragma unroll
      for (int i = 0; i < FM; ++i)
        af[i] = *(const bf16x8*)&lA[(wm * (BM / WM) + i * 16 + lo) * 64 + ks * 32 + lg * 8];
#pragma unroll
      for (int j = 0; j < FN; ++j)
        bfr[j] = *(const bf16x8*)&lB[(wn * (BN / WN) + j * 16 + lo) * 64 + ks * 32 + lg * 8];
      __builtin_amdgcn_s_setprio(1);
#pragma unroll
      for (int i = 0; i < FM; ++i)
#pragma unroll
        for (int j = 0; j < FN; ++j)
          acc[i][j] = __builtin_amdgcn_mfma_f32_16x16x32_bf16(af[i], bfr[j], acc[i][j], 0, 0, 0);
      __builtin_amdgcn_s_setprio(0);
    }
  }

#pragma unroll
  for (int j = 0; j < FN; ++j) {
    int col = n0 + wn * (BN / WN) + j * 16 + lo;
    float bb = bias[col];
#pragma unroll
    for (int i = 0; i < FM; ++i)
#pragma unroll
      for (int r = 0; r < 4; ++r) {
        int row = m0 + wm * (BM / WM) + i * 16 + lg * 4 + r;
        C[(size_t)row * N + col] = acc[i][j][r] + bb;
      }
  }
}

// ---------------- fused per-head LN + split + V transpose ----------------
// grid: 32 bh x 32 s-tiles. Block: 4 waves x 16 s-rows. q scaled by 0.125*log2e.
__global__ __launch_bounds__(256) void k_lnt(
    const float* __restrict__ qkv,   // [B*S][3072]
    const float* __restrict__ qg, const float* __restrict__ qb,
    const float* __restrict__ kg, const float* __restrict__ kb,
    unsigned short* __restrict__ q, unsigned short* __restrict__ k,
    unsigned short* __restrict__ vt) // [BH][64][S]
{
  __shared__ unsigned short t[64 * 72];
  int bid = blockIdx.x;
  int bh = bid >> 5;
  int s0 = (bid & 31) * 64;
  int b = bh >> 4, h = bh & 15;
  int lane = threadIdx.x & 63, wid = threadIdx.x >> 6;
  float gq = qg[lane], bq = qb[lane], gk = kg[lane], bk = kb[lane];

#pragma unroll 4
  for (int it = 0; it < 16; ++it) {
    int sr = wid * 16 + it;
    int s = s0 + sr;
    const float* base = qkv + ((size_t)(b * 2048 + s)) * 3072 + h * 64 + lane;
    float xq = base[0], xk = base[1024], xv = base[2048];
    float muq = xq, muk = xk;
#pragma unroll
    for (int d = 32; d; d >>= 1) { muq += __shfl_xor(muq, d, 64); muk += __shfl_xor(muk, d, 64); }
    muq *= (1.0f / 64.0f); muk *= (1.0f / 64.0f);
    float dq = xq - muq, dk = xk - muk;
    float vq = dq * dq, vk = dk * dk;
#pragma unroll
    for (int d = 32; d; d >>= 1) { vq += __shfl_xor(vq, d, 64); vk += __shfl_xor(vk, d, 64); }
    vq *= (1.0f / 64.0f); vk *= (1.0f / 64.0f);
    float yq = dq * rsqrtf(vq + 1e-5f) * gq + bq;
    float yk = dk * rsqrtf(vk + 1e-5f) * gk + bk;
    size_t o = ((size_t)bh * 2048 + s) * 64 + lane;
    q[o] = f2bf(yq * 0.18033688f);   // 0.125 * log2(e)
    k[o] = f2bf(yk);
    t[sr * 72 + lane] = f2bf(xv);
  }
  __syncthreads();
  int d = threadIdx.x & 63;
#pragma unroll
  for (int it = 0; it < 2; ++it) {
    int cc = (threadIdx.x >> 6) + 4 * it;
    bf16x8 o;
#pragma unroll
    for (int j = 0; j < 8; ++j) o[j] = (short)t[(cc * 8 + j) * 72 + d];
    *(bf16x8*)(vt + ((size_t)bh * 64 + d) * 2048 + s0 + cc * 8) = o;
  }
}

// ---------------- flash attention v4 ----------------
// 512 blocks (XCD-swizzled), 4 waves x 32 q. KVBLK=128, reg-staged LDS dbuf.
// Tree max/sum, permlane32_swap P-assembly, zero-frag MFMA init, setprio.
__global__ __launch_bounds__(256, 2) void k_attn(
    const unsigned short* __restrict__ Q,   // [BH][S][64] (pre-scaled)
    const unsigned short* __restrict__ K,   // [BH][S][64]
    const unsigned short* __restrict__ VT,  // [BH][64][S]
    unsigned short* __restrict__ O)         // [B*S][1024] bf16
{
  __shared__ unsigned short lK[2][128 * 72];
  __shared__ unsigned short lV[2][64 * 136];

  int tid = threadIdx.x;
  int wid = tid >> 6, lane = tid & 63;
  int l31 = lane & 31, hi = lane >> 5;

  int id = blockIdx.x;                       // XCD-bijective (512 % 8 == 0)
  int nid = (id & 7) * 64 + (id >> 3);
  int bh = nid >> 4;
  int q0 = (nid & 15) << 7;
  int q = q0 + wid * 32 + l31;

  const unsigned short* qp = Q + ((size_t)bh * 2048 + q) * 64 + hi * 8;
  bf16x8 qf[4];
#pragma unroll
  for (int s = 0; s < 4; ++s) qf[s] = *(const bf16x8*)(qp + 16 * s);

  const unsigned short* kb = K + (size_t)bh * 2048 * 64;
  const unsigned short* vb = VT + (size_t)bh * 64 * 2048;

  // staging bases: K chunk (tid>>3, tid&7), V chunk (tid>>4, tid&15)
  const unsigned short* kbase = kb + (size_t)(tid >> 3) * 64 + (tid & 7) * 8;
  const unsigned short* vbase = vb + (size_t)(tid >> 4) * 2048 + (tid & 15) * 8;
  const int kloff = (tid >> 3) * 72 + (tid & 7) * 8;     // +2304 per i
  const int vloff = (tid >> 4) * 136 + (tid & 15) * 8;   // +2176 per i

  f32x16 z16;
#pragma unroll
  for (int i = 0; i < 16; ++i) z16[i] = 0.f;

  float m = -1e30f, lsum = 0.0f;
  f32x16 o0 = z16, o1 = z16;

  // prologue: stage tile 0 into buf 0
  bf16x8 kr[4], vr[4];
#pragma unroll
  for (int i = 0; i < 4; ++i) {
    kr[i] = *(const bf16x8*)(kbase + i * 2048);
    vr[i] = *(const bf16x8*)(vbase + i * 32768);
  }
#pragma unroll
  for (int i = 0; i < 4; ++i) {
    *(bf16x8*)&lK[0][kloff + i * 2304] = kr[i];
    *(bf16x8*)&lV[0][vloff + i * 2176] = vr[i];
  }
  const unsigned short* kseq = kbase + 8192;    // tile-1 K src
  const unsigned short* vseq = vbase + 128;     // tile-1 V src

  int p = 0;
  for (int t = 0; t < 16; ++t) {
    if (t < 15) {                               // issue next tile's loads early
#pragma unroll
      for (int i = 0; i < 4; ++i) {
        kr[i] = *(const bf16x8*)(kseq + i * 2048);
        vr[i] = *(const bf16x8*)(vseq + i * 32768);
      }
      kseq += 8192; vseq += 128;
    }
    __syncthreads();

    const unsigned short* bK = lK[p];
    const unsigned short* bV = lV[p];

    // ---- QK^T: 4 fragments of 32 kv, zero-frag init ----
    f32x16 sc[4];
    __builtin_amdgcn_s_setprio(1);
#pragma unroll
    for (int c = 0; c < 4; ++c) {
      bf16x8 kf = *(const bf16x8*)&bK[(c * 32 + l31) * 72 + hi * 8];
      sc[c] = __builtin_amdgcn_mfma_f32_32x32x16_bf16(kf, qf[0], z16, 0, 0, 0);
#pragma unroll
      for (int s = 1; s < 4; ++s) {
        kf = *(const bf16x8*)&bK[(c * 32 + l31) * 72 + (2 * s + hi) * 8];
        sc[c] = __builtin_amdgcn_mfma_f32_32x32x16_bf16(kf, qf[s], sc[c], 0, 0, 0);
      }
    }
    __builtin_amdgcn_s_setprio(0);

    // ---- tree max (depth ~6, not a 64-chain) ----
    float r[16];
#pragma unroll
    for (int i = 0; i < 16; ++i)
      r[i] = fmaxf(fmaxf(sc[0][i], sc[1][i]), fmaxf(sc[2][i], sc[3][i]));
#pragma unroll
    for (int d = 8; d; d >>= 1)
#pragma unroll
      for (int i = 0; i < d; ++i) r[i] = fmaxf(r[i], r[i + d]);
    float pm = fmaxf(r[0], __shfl_xor(r[0], 32, 64));

    if (!__all(pm - m <= 8.0f)) {               // defer-max (T13)
      float mn = fmaxf(m, pm);
      float fac = exp2f(m - mn);
      m = mn;
      lsum *= fac;
#pragma unroll
      for (int i = 0; i < 16; ++i) { o0[i] *= fac; o1[i] *= fac; }
    }

    // ---- exp2 + tree sum ----
#pragma unroll
    for (int c = 0; c < 4; ++c)
#pragma unroll
      for (int i = 0; i < 16; ++i) sc[c][i] = exp2f(sc[c][i] - m);
    float ts[16];
#pragma unroll
    for (int i = 0; i < 16; ++i)
      ts[i] = (sc[0][i] + sc[1][i]) + (sc[2][i] + sc[3][i]);
#pragma unroll
    for (int d = 8; d; d >>= 1)
#pragma unroll
      for (int i = 0; i < d; ++i) ts[i] += ts[i + d];
    lsum += ts[0] + __shfl_xor(ts[0], 32, 64);

    // ---- PV: 8 K-steps; P B-frag via cvt_pk + permlane32_swap ----
#pragma unroll
    for (int s = 0; s < 8; ++s) {
      const f32x16& sf = sc[s >> 1];
      const int rb = (s & 1) * 8;
      unsigned d0 = pkbf(sf[rb + 0], sf[rb + 1]);
      unsigned d1 = pkbf(sf[rb + 2], sf[rb + 3]);
      unsigned d2 = pkbf(sf[rb + 4], sf[rb + 5]);
      unsigned d3 = pkbf(sf[rb + 6], sf[rb + 7]);
      pl32swap(d0, d2);   // dw0=(a0.lo,b0.lo), dw2=(a0.hi,b0.hi)
      pl32swap(d1, d3);
      union { unsigned u[4]; bf16x8 v; } pu;
      pu.u[0] = d0; pu.u[1] = d1; pu.u[2] = d2; pu.u[3] = d3;
      bf16x8 v0 = *(const bf16x8*)&bV[l31 * 136 + (2 * s + hi) * 8];
      bf16x8 v1 = *(const bf16x8*)&bV[(l31 + 32) * 136 + (2 * s + hi) * 8];
      __builtin_amdgcn_s_setprio(1);
      o0 = __builtin_amdgcn_mfma_f32_32x32x16_bf16(v0, pu.v, o0, 0, 0, 0);
      o1 = __builtin_amdgcn_mfma_f32_32x32x16_bf16(v1, pu.v, o1, 0, 0, 0);
      __builtin_amdgcn_s_setprio(0);
    }

    if (t < 15) {                               // write next tile post-compute
#pragma unroll
      for (int i = 0; i < 4; ++i) {
        *(bf16x8*)&lK[p ^ 1][kloff + i * 2304] = kr[i];
        *(bf16x8*)&lV[p ^ 1][vloff + i * 2176] = vr[i];
      }
    }
    p ^= 1;
  }

  // ---- epilogue ----
  float inv = 1.0f / lsum;
  int b = bh >> 4, h = bh & 15;
  unsigned short* ob = O + ((size_t)(b * 2048 + q)) * 1024 + h * 64;
#pragma unroll
  for (int g = 0; g < 4; ++g) {
    uint2 w;
    w.x = pkbf(o0[4 * g + 0] * inv, o0[4 * g + 1] * inv);
    w.y = pkbf(o0[4 * g + 2] * inv, o0[4 * g + 3] * inv);
    *(uint2*)(ob + 8 * g + 4 * hi) = w;
    w.x = pkbf(o1[4 * g + 0] * inv, o1[4 * g + 1] * inv);
    w.y = pkbf(o1[4 * g + 2] * inv, o1[4 * g + 3] * inv);
    *(uint2*)(ob + 32 + 8 * g + 4 * hi) = w;
  }
}

extern "C" void kernel_launch(void* const* d_in, const int* in_sizes, int n_in,
                              void* d_out, int out_size, void* d_ws, size_t ws_size,
                              hipStream_t stream)
{
  (void)in_sizes; (void)n_in; (void)out_size; (void)ws_size;
  const float* x      = (const float*)d_in[0];
  const float* w_qkv  = (const float*)d_in[1];
  const float* b_qkv  = (const float*)d_in[2];
  const float* w_proj = (const float*)d_in[3];
  const float* b_proj = (const float*)d_in[4];
  const float* q_g    = (const float*)d_in[5];
  const float* q_b    = (const float*)d_in[6];
  const float* k_g    = (const float*)d_in[7];
  const float* k_b    = (const float*)d_in[8];
  float* out = (float*)d_out;

  char* p = (char*)d_ws;
  unsigned short* x_bf  = (unsigned short*)p;  p += (size_t)4096 * 1024 * 2;
  unsigned short* wq_bf = (unsigned short*)p;  p += (size_t)3072 * 1024 * 2;
  unsigned short* wp_bf = (unsigned short*)p;  p += (size_t)1024 * 1024 * 2;
  float*          qkv   = (float*)p;           p += (size_t)4096 * 3072 * 4;
  unsigned short* qh    = (unsigned short*)p;  p += (size_t)32 * 2048 * 64 * 2;
  unsigned short* kh    = (unsigned short*)p;  p += (size_t)32 * 2048 * 64 * 2;
  unsigned short* vt    = (unsigned short*)p;  p += (size_t)32 * 64 * 2048 * 2;
  unsigned short* ao    = (unsigned short*)p;  p += (size_t)4096 * 1024 * 2;

  k_cvt<<<4096, 256, 0, stream>>>(x,      x_bf,  1048576);
  k_cvt<<<3072, 256, 0, stream>>>(w_qkv,  wq_bf,  786432);
  k_cvt<<<1024, 256, 0, stream>>>(w_proj, wp_bf,  262144);

  k_gemm<128, 128, 2, 2><<<dim3(24, 32), 256, 0, stream>>>(x_bf, wq_bf, b_qkv, qkv, 4096, 3072, 1024);
  k_lnt<<<1024, 256, 0, stream>>>(qkv, q_g, q_b, k_g, k_b, qh, kh, vt);
  k_attn<<<512, 256, 0, stream>>>(qh, kh, vt, ao);
  k_gemm<64, 128, 1, 4><<<dim3(8, 64), 256, 0, stream>>>(ao, wp_bf, b_proj, out, 4096, 1024, 1024);
}